// Round 1
// baseline (2083.961 us; speedup 1.0000x reference)
//
#include <hip/hip_runtime.h>
#include <stdint.h>

#define NUM_C 16
#define NUM_B 8
#define INS_BLOCKS 1024
#define EMPTY_KEY 0xFFFFFFFFu

__device__ __forceinline__ unsigned hash_u32(unsigned h) {
    h ^= h >> 16; h *= 0x85ebca6bu;
    h ^= h >> 13; h *= 0xc2b2ae35u;
    h ^= h >> 16;
    return h;
}

// Insert all (value,label) of one batch into per-class hash tables; also
// accumulate per-block partial sums/counts (written, not atomically added).
__global__ void __launch_bounds__(256)
insert_kernel(const float* __restrict__ x, const int* __restrict__ t, int n,
              unsigned* __restrict__ keys, unsigned* __restrict__ counts,
              double* __restrict__ psum,   // [INS_BLOCKS][NUM_C] for this batch
              unsigned* __restrict__ pcnt, // [INS_BLOCKS][NUM_C]
              int s_log2)
{
    __shared__ float ssum[NUM_C];
    __shared__ unsigned scnt[NUM_C];
    if (threadIdx.x < NUM_C) { ssum[threadIdx.x] = 0.f; scnt[threadIdx.x] = 0u; }
    __syncthreads();

    const unsigned mask = (1u << s_log2) - 1u;
    const int stride = gridDim.x * blockDim.x;
    for (int i = blockIdx.x * blockDim.x + threadIdx.x; i < n; i += stride) {
        float v = x[i];
        int c = t[i];
        unsigned key = __float_as_uint(v);
        if (key == 0x80000000u) key = 0u;   // canonicalize -0.0 == +0.0
        unsigned h = hash_u32(key) & mask;
        const unsigned base = (unsigned)c << s_log2;
        for (;;) {
            unsigned idx = base + h;
            unsigned cur = keys[idx];
            if (cur == key) { atomicAdd(&counts[idx], 1u); break; }
            if (cur == EMPTY_KEY) {
                unsigned old = atomicCAS(&keys[idx], EMPTY_KEY, key);
                if (old == EMPTY_KEY || old == key) { atomicAdd(&counts[idx], 1u); break; }
            }
            h = (h + 1u) & mask;
        }
        atomicAdd(&ssum[c], v);
        atomicAdd(&scnt[c], 1u);
    }
    __syncthreads();
    if (threadIdx.x < NUM_C) {
        psum[blockIdx.x * NUM_C + threadIdx.x] = (double)ssum[threadIdx.x];
        pcnt[blockIdx.x * NUM_C + threadIdx.x] = scnt[threadIdx.x];
    }
}

// Scan the tables: per class keep max over packed (count<<32 | (2^32-1 - ord)).
// ord() is an order-preserving float->uint map, so max pack = (max count,
// then min value) -- exactly the reference's mode tie-break. Also covers the
// degenerate all-count-1 case (mode = group min).
__global__ void __launch_bounds__(256)
scan_kernel(const unsigned* __restrict__ keys, const unsigned* __restrict__ counts,
            unsigned long long* __restrict__ best,  // [NUM_C] for this batch
            int s_log2)
{
    __shared__ unsigned long long sbest[NUM_C];
    if (threadIdx.x < NUM_C) sbest[threadIdx.x] = 0ull;
    __syncthreads();

    const unsigned nchunks = (NUM_C << s_log2) >> 4;   // 16 slots per chunk
    const unsigned stride = gridDim.x * blockDim.x;
    for (unsigned chunk = blockIdx.x * blockDim.x + threadIdx.x;
         chunk < nchunks; chunk += stride) {
        const unsigned slot0 = chunk << 4;
        const unsigned c = slot0 >> s_log2;   // chunk never crosses a class boundary
        const uint4* kp = (const uint4*)(keys + slot0);
        const uint4* cp = (const uint4*)(counts + slot0);
        unsigned long long lb = 0ull;
        #pragma unroll
        for (int q = 0; q < 4; ++q) {
            uint4 kv = kp[q];
            uint4 cv = cp[q];
            unsigned ks[4] = {kv.x, kv.y, kv.z, kv.w};
            unsigned cs[4] = {cv.x, cv.y, cv.z, cv.w};
            #pragma unroll
            for (int j = 0; j < 4; ++j) {
                unsigned k = ks[j];
                if (k != EMPTY_KEY) {
                    unsigned ord = (k & 0x80000000u) ? ~k : (k | 0x80000000u);
                    unsigned long long p = ((unsigned long long)cs[j] << 32)
                                         | (unsigned long long)(0xFFFFFFFFu - ord);
                    if (p > lb) lb = p;
                }
            }
        }
        if (lb) atomicMax(&sbest[c], lb);
    }
    __syncthreads();
    if (threadIdx.x < NUM_C && sbest[threadIdx.x])
        atomicMax(&best[threadIdx.x], sbest[threadIdx.x]);
}

// 128 threads, one per (b,c): reduce per-block partials, decode mode,
// out = sum_{b,c}(sum - cnt*mode) / (B*N).
__global__ void __launch_bounds__(128)
finalize_kernel(const double* __restrict__ psum,      // [NUM_B][INS_BLOCKS][NUM_C]
                const unsigned* __restrict__ pcnt,
                const unsigned long long* __restrict__ best, // [NUM_B][NUM_C]
                float* __restrict__ out, double inv_total)
{
    __shared__ double acc[NUM_B * NUM_C];
    const int i = threadIdx.x;              // i = b*16 + c
    const int b = i >> 4, c = i & 15;

    double s = 0.0;
    unsigned long long cnt = 0ull;
    const double* ps = psum + (size_t)b * INS_BLOCKS * NUM_C + c;
    const unsigned* pc = pcnt + (size_t)b * INS_BLOCKS * NUM_C + c;
    for (int g = 0; g < INS_BLOCKS; ++g) {
        s += ps[(size_t)g * NUM_C];
        cnt += pc[(size_t)g * NUM_C];
    }

    double term = 0.0;
    if (cnt > 0ull) {
        unsigned long long p = best[i];
        unsigned ord = 0xFFFFFFFFu - (unsigned)(p & 0xFFFFFFFFull);
        unsigned ub = (ord & 0x80000000u) ? (ord ^ 0x80000000u) : ~ord;
        float mode = __uint_as_float(ub);
        term = s - (double)cnt * (double)mode;
    }
    acc[i] = term;
    __syncthreads();
    for (int st = 64; st > 0; st >>= 1) {
        if (i < st) acc[i] += acc[i + st];
        __syncthreads();
    }
    if (i == 0) out[0] = (float)(acc[0] * inv_total);
}

extern "C" void kernel_launch(void* const* d_in, const int* in_sizes, int n_in,
                              void* d_out, int out_size, void* d_ws, size_t ws_size,
                              hipStream_t stream)
{
    const float* x = (const float*)d_in[0];
    const int*   t = (const int*)d_in[1];
    // d_in[2] is num_classes (==16, hardcoded as NUM_C).

    const long long total = in_sizes[0];
    const long long N = total / NUM_B;

    // Workspace layout:
    //   best  : NUM_B*NUM_C u64                       (1 KiB)
    //   psum  : NUM_B*INS_BLOCKS*NUM_C double         (1 MiB)
    //   pcnt  : NUM_B*INS_BLOCKS*NUM_C u32            (512 KiB)
    //   keys  : NUM_C<<s_log2 u32                     (16 MiB @ s_log2=18)
    //   counts: NUM_C<<s_log2 u32                     (16 MiB)
    char* ws = (char*)d_ws;
    unsigned long long* best = (unsigned long long*)ws;
    size_t off = (size_t)NUM_B * NUM_C * 8;
    double* psum = (double*)(ws + off);
    off += (size_t)NUM_B * INS_BLOCKS * NUM_C * 8;
    unsigned* pcnt = (unsigned*)(ws + off);
    off += (size_t)NUM_B * INS_BLOCKS * NUM_C * 4;
    off = (off + 4095) & ~(size_t)4095;

    int s_log2 = 18;
    if (ws_size < off + 2ull * ((size_t)NUM_C << 18) * 4ull) s_log2 = 17;
    const size_t tbl_bytes = ((size_t)NUM_C << s_log2) * 4ull;
    unsigned* keys   = (unsigned*)(ws + off);
    unsigned* counts = (unsigned*)(ws + off + tbl_bytes);

    hipMemsetAsync(best, 0, (size_t)NUM_B * NUM_C * 8, stream);
    for (int b = 0; b < NUM_B; ++b) {
        hipMemsetAsync(keys, 0xFF, tbl_bytes, stream);
        hipMemsetAsync(counts, 0, tbl_bytes, stream);
        insert_kernel<<<INS_BLOCKS, 256, 0, stream>>>(
            x + (size_t)b * N, t + (size_t)b * N, (int)N,
            keys, counts,
            psum + (size_t)b * INS_BLOCKS * NUM_C,
            pcnt + (size_t)b * INS_BLOCKS * NUM_C,
            s_log2);
        scan_kernel<<<INS_BLOCKS, 256, 0, stream>>>(
            keys, counts, best + (size_t)b * NUM_C, s_log2);
    }
    finalize_kernel<<<1, 128, 0, stream>>>(
        psum, pcnt, best, (float*)d_out,
        1.0 / (double)((double)NUM_B * (double)N));
}

// Round 2
// 986.342 us; speedup vs baseline: 2.1128x; 2.1128x over previous
//
#include <hip/hip_runtime.h>
#include <stdint.h>

#define NUM_C 16
#define NUM_B 8
#define RANGES 128                      // hash sub-ranges per class
#define NBKT_PER_B (NUM_C * RANGES)     // 2048 buckets per batch
#define CAP_DEFAULT 1536                // slots per bucket (mean ~976, +18 sigma)
#define BLKS_PER_B 128                  // scatter blocks per batch
#define TAB_SLOTS 2048                  // LDS hash slots per bucket (load ~0.48)

__device__ __forceinline__ unsigned hash_u32(unsigned h) {
    h ^= h >> 16; h *= 0x85ebca6bu;
    h ^= h >> 13; h *= 0xc2b2ae35u;
    h ^= h >> 16;
    return h;
}

// Pass 1 (per batch range): stream x,t once. Accumulate per-(block,class)
// sums/counts, and scatter canonicalized key bits into per-(class,hash-range)
// bucket regions via global atomic cursors. One 4B write per item.
__global__ void __launch_bounds__(256)
scatter_kernel(const float* __restrict__ x, const int* __restrict__ t,
               long long N, int bbase,
               unsigned* __restrict__ cursor,   // [nb*NBKT_PER_B], zeroed
               unsigned* __restrict__ keysout,  // [nb*NBKT_PER_B*cap]
               double* __restrict__ psum,       // [NUM_B][BLKS_PER_B][NUM_C]
               unsigned* __restrict__ pcnt,     // [NUM_B][BLKS_PER_B][NUM_C]
               unsigned cap)
{
    const int lb  = blockIdx.x / BLKS_PER_B;   // batch index local to this round
    const int blk = blockIdx.x % BLKS_PER_B;
    const int b   = bbase + lb;

    __shared__ float    ssum[NUM_C];
    __shared__ unsigned scnt[NUM_C];
    if (threadIdx.x < NUM_C) { ssum[threadIdx.x] = 0.f; scnt[threadIdx.x] = 0u; }
    __syncthreads();

    const float* xb = x + (size_t)b * N;
    const int*   tb = t + (size_t)b * N;
    unsigned* cur = cursor  + (size_t)lb * NBKT_PER_B;
    unsigned* ko  = keysout + (size_t)lb * NBKT_PER_B * cap;

    const long long n4 = N >> 2;
    const long long stride = (long long)BLKS_PER_B * 256;
    for (long long i = (long long)blk * 256 + threadIdx.x; i < n4; i += stride) {
        float4 v  = ((const float4*)xb)[i];
        int4   cc = ((const int4*)tb)[i];
        float vs[4] = {v.x, v.y, v.z, v.w};
        int   cs[4] = {cc.x, cc.y, cc.z, cc.w};
        #pragma unroll
        for (int j = 0; j < 4; ++j) {
            float vv = vs[j];
            int   c  = cs[j];
            unsigned key = __float_as_uint(vv);
            if (key == 0x80000000u) key = 0u;          // -0.0 == +0.0
            unsigned h   = hash_u32(key);
            unsigned bkt = ((unsigned)c << 7) | (h >> 25);   // top 7 bits
            unsigned pos = atomicAdd(&cur[bkt], 1u);
            if (pos < cap) ko[(size_t)bkt * cap + pos] = key;
            atomicAdd(&ssum[c], vv);
            atomicAdd(&scnt[c], 1u);
        }
    }
    // scalar tail (N % 4)
    for (long long i = (n4 << 2) + (long long)blk * 256 + threadIdx.x; i < N;
         i += stride) {
        float vv = xb[i];
        int   c  = tb[i];
        unsigned key = __float_as_uint(vv);
        if (key == 0x80000000u) key = 0u;
        unsigned h   = hash_u32(key);
        unsigned bkt = ((unsigned)c << 7) | (h >> 25);
        unsigned pos = atomicAdd(&cur[bkt], 1u);
        if (pos < cap) ko[(size_t)bkt * cap + pos] = key;
        atomicAdd(&ssum[c], vv);
        atomicAdd(&scnt[c], 1u);
    }
    __syncthreads();
    if (threadIdx.x < NUM_C) {
        psum[((size_t)b * BLKS_PER_B + blk) * NUM_C + threadIdx.x] =
            (double)ssum[threadIdx.x];
        pcnt[((size_t)b * BLKS_PER_B + blk) * NUM_C + threadIdx.x] =
            scnt[threadIdx.x];
    }
}

// Pass 2: one block per bucket. Build a packed (count<<32 | key) hash table
// in LDS, then fold the bucket into per-(b,c) best = max(count<<32 | (2^32-1
// - ord(value))) -- max count, ties -> smallest value (reference tie-break).
__global__ void __launch_bounds__(256)
mode_kernel(const unsigned* __restrict__ cursor,
            const unsigned* __restrict__ keysout,
            unsigned long long* __restrict__ best,   // [NUM_B*NUM_C], zeroed
            int bbase, unsigned cap)
{
    const unsigned bkt = blockIdx.x;             // local bucket id
    const unsigned lb  = bkt >> 11;              // / NBKT_PER_B
    const unsigned c   = (bkt >> 7) & 15u;

    __shared__ unsigned long long tab[TAB_SLOTS];
    __shared__ unsigned long long red[256];
    for (int i = threadIdx.x; i < TAB_SLOTS; i += 256) tab[i] = 0ull;
    __syncthreads();

    unsigned cnt = cursor[bkt];
    if (cnt > cap) cnt = cap;
    const unsigned* keys = keysout + (size_t)bkt * cap;

    for (unsigned i = threadIdx.x; i < cnt; i += 256) {
        unsigned key = keys[i];
        unsigned h = hash_u32(key) & (TAB_SLOTS - 1);   // low 11 bits
        unsigned long long pk = (1ull << 32) | (unsigned long long)key;
        for (;;) {
            unsigned long long curv = tab[h];
            if (curv != 0ull && (unsigned)curv == key) {
                atomicAdd(&tab[h], 1ull << 32); break;
            }
            if (curv == 0ull) {
                unsigned long long old = atomicCAS(&tab[h], 0ull, pk);
                if (old == 0ull) break;
                if ((unsigned)old == key) { atomicAdd(&tab[h], 1ull << 32); break; }
            }
            h = (h + 1u) & (TAB_SLOTS - 1);
        }
    }
    __syncthreads();

    unsigned long long lbst = 0ull;
    for (int s = threadIdx.x; s < TAB_SLOTS; s += 256) {
        unsigned long long curv = tab[s];
        if (curv) {
            unsigned k  = (unsigned)curv;
            unsigned ct = (unsigned)(curv >> 32);
            unsigned ord = (k & 0x80000000u) ? ~k : (k | 0x80000000u);
            unsigned long long p = ((unsigned long long)ct << 32)
                                 | (unsigned long long)(0xFFFFFFFFu - ord);
            if (p > lbst) lbst = p;
        }
    }
    red[threadIdx.x] = lbst;
    __syncthreads();
    for (int st = 128; st > 0; st >>= 1) {
        if (threadIdx.x < st && red[threadIdx.x + st] > red[threadIdx.x])
            red[threadIdx.x] = red[threadIdx.x + st];
        __syncthreads();
    }
    if (threadIdx.x == 0 && red[0])
        atomicMax(&best[((unsigned)bbase + lb) * NUM_C + c], red[0]);
}

// 128 threads, one per (b,c): reduce partials, decode mode,
// out = sum_{b,c}(sum - cnt*mode) / (B*N).
__global__ void __launch_bounds__(128)
finalize_kernel(const double* __restrict__ psum,
                const unsigned* __restrict__ pcnt,
                const unsigned long long* __restrict__ best,
                float* __restrict__ out, double inv_total)
{
    __shared__ double acc[NUM_B * NUM_C];
    const int i = threadIdx.x;
    const int b = i >> 4, c = i & 15;

    double s = 0.0;
    unsigned long long cnt = 0ull;
    const double*   ps = psum + (size_t)b * BLKS_PER_B * NUM_C + c;
    const unsigned* pc = pcnt + (size_t)b * BLKS_PER_B * NUM_C + c;
    for (int g = 0; g < BLKS_PER_B; ++g) {
        s   += ps[(size_t)g * NUM_C];
        cnt += pc[(size_t)g * NUM_C];
    }

    double term = 0.0;
    if (cnt > 0ull) {
        unsigned long long p = best[i];
        unsigned ord = 0xFFFFFFFFu - (unsigned)(p & 0xFFFFFFFFull);
        unsigned ub  = (ord & 0x80000000u) ? (ord ^ 0x80000000u) : ~ord;
        float mode = __uint_as_float(ub);
        term = s - (double)cnt * (double)mode;
    }
    acc[i] = term;
    __syncthreads();
    for (int st = 64; st > 0; st >>= 1) {
        if (i < st) acc[i] += acc[i + st];
        __syncthreads();
    }
    if (i == 0) out[0] = (float)(acc[0] * inv_total);
}

extern "C" void kernel_launch(void* const* d_in, const int* in_sizes, int n_in,
                              void* d_out, int out_size, void* d_ws, size_t ws_size,
                              hipStream_t stream)
{
    const float* x = (const float*)d_in[0];
    const int*   t = (const int*)d_in[1];

    const long long total = in_sizes[0];
    const long long N = total / NUM_B;

    // Workspace layout (fixed part ~262 KiB, then keysout):
    char* ws = (char*)d_ws;
    size_t off = 0;
    unsigned long long* best = (unsigned long long*)(ws + off);
    off += (size_t)NUM_B * NUM_C * 8;                       // 1 KiB
    double* psum = (double*)(ws + off);
    off += (size_t)NUM_B * BLKS_PER_B * NUM_C * 8;          // 128 KiB
    unsigned* pcnt = (unsigned*)(ws + off);
    off += (size_t)NUM_B * BLKS_PER_B * NUM_C * 4;          // 64 KiB
    unsigned* cursor = (unsigned*)(ws + off);
    off += (size_t)NUM_B * NBKT_PER_B * 4;                  // 64 KiB (max nb=8)
    off = (off + 255) & ~(size_t)255;
    unsigned* keysout = (unsigned*)(ws + off);

    size_t remaining = ws_size - off;
    unsigned cap = CAP_DEFAULT;
    size_t per_b = (size_t)NBKT_PER_B * cap * 4;            // 12.6 MB / batch
    int nb = (int)(remaining / per_b);
    if (nb < 1) {                                            // tiny ws fallback
        nb = 1;
        cap = (unsigned)(remaining / ((size_t)NBKT_PER_B * 4));
    }
    if (nb > NUM_B) nb = NUM_B;

    hipMemsetAsync(best, 0, (size_t)NUM_B * NUM_C * 8, stream);
    for (int r = 0; r < NUM_B; r += nb) {
        int nbr = (NUM_B - r < nb) ? (NUM_B - r) : nb;
        hipMemsetAsync(cursor, 0, (size_t)nbr * NBKT_PER_B * 4, stream);
        scatter_kernel<<<nbr * BLKS_PER_B, 256, 0, stream>>>(
            x, t, N, r, cursor, keysout, psum, pcnt, cap);
        mode_kernel<<<nbr * NBKT_PER_B, 256, 0, stream>>>(
            cursor, keysout, best, r, cap);
    }
    finalize_kernel<<<1, 128, 0, stream>>>(
        psum, pcnt, best, (float*)d_out,
        1.0 / ((double)NUM_B * (double)N));
}

// Round 3
// 481.948 us; speedup vs baseline: 4.3240x; 2.0466x over previous
//
#include <hip/hip_runtime.h>
#include <stdint.h>

#define NUM_C 16
#define NUM_B 8
#define RANGES 32                       // hash sub-ranges per class
#define NBKT (NUM_C * RANGES)           // 512 buckets per batch
#define CAP_DEFAULT 4608                // slots/bucket (mean ~3906, +11 sigma)
#define FRAG 16                         // LDS staging slots per bucket
#define SCAT_BLKS 128                   // scatter blocks per batch
#define TAB_SLOTS 8192                  // LDS hash slots (load ~0.48)

__device__ __forceinline__ unsigned hash_u32(unsigned h) {
    h ^= h >> 16; h *= 0x85ebca6bu;
    h ^= h >> 13; h *= 0xc2b2ae35u;
    h ^= h >> 16;
    return h;
}

__device__ __forceinline__ void push_item(
    float vv, int c, unsigned* lbuf, unsigned* lfill,
    unsigned* __restrict__ cur, unsigned* __restrict__ ko, unsigned cap)
{
    unsigned key = __float_as_uint(vv);
    if (key == 0x80000000u) key = 0u;            // -0.0 == +0.0
    unsigned h   = hash_u32(key);
    unsigned bkt = ((unsigned)c << 5) | (h >> 27);   // class | top-5 hash bits
    unsigned p = atomicAdd(&lfill[bkt], 1u);
    if (p < FRAG) {
        lbuf[bkt * FRAG + p] = key;              // staged; flushed in bulk
    } else {                                     // rare overflow: direct write
        unsigned g = atomicAdd(&cur[bkt], 1u);
        if (g < cap) ko[(size_t)bkt * cap + g] = key;
    }
}

// Pass 1: stream x,t once; bin canonicalized key bits into per-(class,range)
// bucket regions. LDS-staged: one cursor atomic + contiguous stores per ~16
// items instead of one random 4B store (and dirty 64B line) per item.
__global__ void __launch_bounds__(256)
scatter_kernel(const float* __restrict__ x, const int* __restrict__ t,
               long long N, int bbase,
               unsigned* __restrict__ cursor,   // [nb*NBKT], zeroed
               unsigned* __restrict__ keysout,  // [nb*NBKT*cap]
               unsigned cap)
{
    const int lb  = blockIdx.x / SCAT_BLKS;
    const int blk = blockIdx.x % SCAT_BLKS;
    const int b   = bbase + lb;

    __shared__ unsigned lbuf[NBKT * FRAG];       // 32 KiB
    __shared__ unsigned lfill[NBKT];             // 2 KiB
    for (int i = threadIdx.x; i < NBKT; i += 256) lfill[i] = 0u;
    __syncthreads();

    const float* xb = x + (size_t)b * N;
    const int*   tb = t + (size_t)b * N;
    unsigned* cur = cursor  + (size_t)lb * NBKT;
    unsigned* ko  = keysout + (size_t)lb * NBKT * cap;

    const long long n4     = N >> 2;
    const long long stride = (long long)SCAT_BLKS * 256;
    const long long iters  = (n4 + stride - 1) / stride;
    long long i = (long long)blk * 256 + threadIdx.x;

    for (long long it = 0; it < iters; ++it, i += stride) {
        if (i < n4) {
            float4 v  = ((const float4*)xb)[i];
            int4   cc = ((const int4*)tb)[i];
            push_item(v.x, cc.x, lbuf, lfill, cur, ko, cap);
            push_item(v.y, cc.y, lbuf, lfill, cur, ko, cap);
            push_item(v.z, cc.z, lbuf, lfill, cur, ko, cap);
            push_item(v.w, cc.w, lbuf, lfill, cur, ko, cap);
        }
        if ((it & 3) == 3 || it == iters - 1) {
            __syncthreads();
            for (int bkt = threadIdx.x; bkt < NBKT; bkt += 256) {
                unsigned f = lfill[bkt];
                if (f) {
                    if (f > FRAG) f = FRAG;      // overflow went direct
                    unsigned g = atomicAdd(&cur[bkt], f);
                    for (unsigned j = 0; j < f; ++j)
                        if (g + j < cap)
                            ko[(size_t)bkt * cap + g + j] = lbuf[bkt * FRAG + j];
                    lfill[bkt] = 0u;
                }
            }
            __syncthreads();
        }
    }
    // scalar tail (N % 4): direct path, no LDS
    if (blk == 0) {
        for (long long j = (n4 << 2) + threadIdx.x; j < N; j += 256) {
            float vv = xb[j];
            int   c  = tb[j];
            unsigned key = __float_as_uint(vv);
            if (key == 0x80000000u) key = 0u;
            unsigned h   = hash_u32(key);
            unsigned bkt = ((unsigned)c << 5) | (h >> 27);
            unsigned g = atomicAdd(&cur[bkt], 1u);
            if (g < cap) ko[(size_t)bkt * cap + g] = key;
        }
    }
}

// Pass 2: one block per bucket. Build packed (count<<32 | key) LDS table,
// fold into best = max(count<<32 | (2^32-1 - ord(value))) -- max count,
// ties -> smallest value. Also computes the bucket's exact f64 value-sum
// (scatter no longer accumulates sums).
__global__ void __launch_bounds__(256)
mode_kernel(const unsigned* __restrict__ cursor,
            const unsigned* __restrict__ keysout,
            unsigned long long* __restrict__ best,   // [NUM_B*NUM_C], zeroed
            double* __restrict__ psum,               // [NUM_B*NBKT]
            unsigned* __restrict__ pcnt,             // [NUM_B*NBKT]
            int bbase, unsigned cap)
{
    const unsigned lb   = blockIdx.x / NBKT;
    const unsigned bktl = blockIdx.x % NBKT;
    const unsigned c    = bktl >> 5;
    const unsigned b    = (unsigned)bbase + lb;

    __shared__ unsigned long long tab[TAB_SLOTS];    // 64 KiB
    __shared__ unsigned long long red[256];
    __shared__ double dred[256];
    for (int i = threadIdx.x; i < TAB_SLOTS; i += 256) tab[i] = 0ull;
    __syncthreads();

    const unsigned cnt_raw = cursor[lb * NBKT + bktl];
    unsigned cnt = cnt_raw < cap ? cnt_raw : cap;
    const unsigned* keys = keysout + ((size_t)lb * NBKT + bktl) * cap;

    double ls = 0.0;
    for (unsigned i = threadIdx.x; i < cnt; i += 256) {
        unsigned key = keys[i];
        ls += (double)__uint_as_float(key);
        unsigned h = hash_u32(key) & (TAB_SLOTS - 1);
        unsigned long long pk = (1ull << 32) | (unsigned long long)key;
        for (;;) {
            unsigned long long curv = tab[h];
            if (curv != 0ull && (unsigned)curv == key) {
                atomicAdd(&tab[h], 1ull << 32); break;
            }
            if (curv == 0ull) {
                unsigned long long old = atomicCAS(&tab[h], 0ull, pk);
                if (old == 0ull) break;
                if ((unsigned)old == key) { atomicAdd(&tab[h], 1ull << 32); break; }
            }
            h = (h + 1u) & (TAB_SLOTS - 1);
        }
    }
    __syncthreads();

    unsigned long long lbst = 0ull;
    for (int s = threadIdx.x; s < TAB_SLOTS; s += 256) {
        unsigned long long curv = tab[s];
        if (curv) {
            unsigned k  = (unsigned)curv;
            unsigned ct = (unsigned)(curv >> 32);
            unsigned ord = (k & 0x80000000u) ? ~k : (k | 0x80000000u);
            unsigned long long p = ((unsigned long long)ct << 32)
                                 | (unsigned long long)(0xFFFFFFFFu - ord);
            if (p > lbst) lbst = p;
        }
    }
    red[threadIdx.x]  = lbst;
    dred[threadIdx.x] = ls;
    __syncthreads();
    for (int st = 128; st > 0; st >>= 1) {
        if (threadIdx.x < st) {
            if (red[threadIdx.x + st] > red[threadIdx.x])
                red[threadIdx.x] = red[threadIdx.x + st];
            dred[threadIdx.x] += dred[threadIdx.x + st];
        }
        __syncthreads();
    }
    if (threadIdx.x == 0) {
        psum[b * NBKT + bktl] = dred[0];
        pcnt[b * NBKT + bktl] = cnt_raw;
        if (red[0]) atomicMax(&best[b * NUM_C + c], red[0]);
    }
}

// 128 threads, one per (b,c): fold the 32 range-buckets, decode mode,
// out = sum_{b,c}(sum - cnt*mode) / (B*N).
__global__ void __launch_bounds__(128)
finalize_kernel(const double* __restrict__ psum,
                const unsigned* __restrict__ pcnt,
                const unsigned long long* __restrict__ best,
                float* __restrict__ out, double inv_total)
{
    __shared__ double acc[NUM_B * NUM_C];
    const int i = threadIdx.x;
    const int b = i >> 4, c = i & 15;

    double s = 0.0;
    unsigned long long cnt = 0ull;
    const double*   ps = psum + (size_t)b * NBKT + ((size_t)c << 5);
    const unsigned* pc = pcnt + (size_t)b * NBKT + ((size_t)c << 5);
    for (int r = 0; r < RANGES; ++r) { s += ps[r]; cnt += pc[r]; }

    double term = 0.0;
    if (cnt > 0ull) {
        unsigned long long p = best[i];
        unsigned ord = 0xFFFFFFFFu - (unsigned)(p & 0xFFFFFFFFull);
        unsigned ub  = (ord & 0x80000000u) ? (ord ^ 0x80000000u) : ~ord;
        float mode = __uint_as_float(ub);
        term = s - (double)cnt * (double)mode;
    }
    acc[i] = term;
    __syncthreads();
    for (int st = 64; st > 0; st >>= 1) {
        if (i < st) acc[i] += acc[i + st];
        __syncthreads();
    }
    if (i == 0) out[0] = (float)(acc[0] * inv_total);
}

extern "C" void kernel_launch(void* const* d_in, const int* in_sizes, int n_in,
                              void* d_out, int out_size, void* d_ws, size_t ws_size,
                              hipStream_t stream)
{
    const float* x = (const float*)d_in[0];
    const int*   t = (const int*)d_in[1];

    const long long total = in_sizes[0];
    const long long N = total / NUM_B;

    // Workspace: best 1K | psum 32K | pcnt 16K | cursor 16K | keysout
    char* ws = (char*)d_ws;
    size_t off = 0;
    unsigned long long* best = (unsigned long long*)(ws + off);
    off += (size_t)NUM_B * NUM_C * 8;
    double* psum = (double*)(ws + off);
    off += (size_t)NUM_B * NBKT * 8;
    unsigned* pcnt = (unsigned*)(ws + off);
    off += (size_t)NUM_B * NBKT * 4;
    unsigned* cursor = (unsigned*)(ws + off);
    off += (size_t)NUM_B * NBKT * 4;
    off = (off + 255) & ~(size_t)255;
    unsigned* keysout = (unsigned*)(ws + off);

    size_t remaining = ws_size - off;
    unsigned cap = CAP_DEFAULT;
    size_t per_b = (size_t)NBKT * cap * 4;               // 9.4 MB / batch
    int nb = (int)(remaining / per_b);
    if (nb < 1) {                                        // tiny-ws fallback
        nb = 1;
        cap = (unsigned)(remaining / ((size_t)NBKT * 4)) & ~15u;
    }
    if (nb > NUM_B) nb = NUM_B;

    hipMemsetAsync(best, 0, (size_t)NUM_B * NUM_C * 8, stream);
    for (int r = 0; r < NUM_B; r += nb) {
        int nbr = (NUM_B - r < nb) ? (NUM_B - r) : nb;
        hipMemsetAsync(cursor, 0, (size_t)nbr * NBKT * 4, stream);
        scatter_kernel<<<nbr * SCAT_BLKS, 256, 0, stream>>>(
            x, t, N, r, cursor, keysout, cap);
        mode_kernel<<<nbr * NBKT, 256, 0, stream>>>(
            cursor, keysout, best, psum, pcnt, r, cap);
    }
    finalize_kernel<<<1, 128, 0, stream>>>(
        psum, pcnt, best, (float*)d_out,
        1.0 / ((double)NUM_B * (double)N));
}

// Round 4
// 386.196 us; speedup vs baseline: 5.3961x; 1.2479x over previous
//
#include <hip/hip_runtime.h>
#include <stdint.h>

#define NUM_C 16
#define NUM_B 8
#define RANGES 64                        // hash sub-ranges per class
#define NBKT (NUM_C * RANGES)            // 1024 buckets per batch
#define CHUNK 8192                       // items per scatter block
#define TAB_SLOTS 4096                   // LDS hash slots (load ~0.48)

__device__ __forceinline__ unsigned hash_u32(unsigned h) {
    h ^= h >> 16; h *= 0x85ebca6bu;
    h ^= h >> 13; h *= 0xc2b2ae35u;
    h ^= h >> 16;
    return h;
}

__device__ __forceinline__ unsigned canon_key(float v) {
    unsigned k = __float_as_uint(v);
    return (k == 0x80000000u) ? 0u : k;          // -0.0 == +0.0
}
__device__ __forceinline__ unsigned bucket_of(unsigned key, int c) {
    return ((unsigned)c << 6) | (hash_u32(key) >> 26);
}

// Pass 1: per-block counting sort. Each block owns a contiguous CHUNK of one
// batch: histogram buckets in LDS, prefix-sum, scatter into LDS, write the
// bucket-sorted chunk back fully coalesced (uint4). Dense output: no caps,
// no global cursors, exact counts. Segment starts -> offs[] (monotone, so
// count(seg,bkt) = offs[next] - offs[cur]; sentinel at end = N).
__global__ void __launch_bounds__(256)
scatter_kernel(const float* __restrict__ x, const int* __restrict__ t,
               long long N, int bbase, int nblk,
               unsigned* __restrict__ keysout,   // [nb][N] dense
               unsigned* __restrict__ offs)      // [nb][nblk*NBKT + 1]
{
    __shared__ unsigned hist[NBKT];              // 4 KiB (counts -> cursors)
    __shared__ unsigned lout[CHUNK];             // 32 KiB
    __shared__ unsigned sscan[256];              // 1 KiB

    const int lb   = blockIdx.x / nblk;
    const int blk  = blockIdx.x % nblk;
    const int b    = bbase + lb;
    const long long base = (long long)blk * CHUNK;
    const int count = (int)((N - base < CHUNK) ? (N - base) : CHUNK);

    const float* xb = x + (size_t)b * N + base;
    const int*   tb = t + (size_t)b * N + base;

    for (int i = threadIdx.x; i < NBKT; i += 256) hist[i] = 0u;
    __syncthreads();

    const bool vec_ok = ((N & 3) == 0);          // alignment of float4 paths
    const int n4 = vec_ok ? (count >> 2) : 0;

    // ---- pass A: histogram ----
    for (int i = threadIdx.x; i < n4; i += 256) {
        float4 v  = ((const float4*)xb)[i];
        int4   cc = ((const int4*)tb)[i];
        atomicAdd(&hist[bucket_of(canon_key(v.x), cc.x)], 1u);
        atomicAdd(&hist[bucket_of(canon_key(v.y), cc.y)], 1u);
        atomicAdd(&hist[bucket_of(canon_key(v.z), cc.z)], 1u);
        atomicAdd(&hist[bucket_of(canon_key(v.w), cc.w)], 1u);
    }
    for (int i = (n4 << 2) + threadIdx.x; i < count; i += 256)
        atomicAdd(&hist[bucket_of(canon_key(xb[i]), tb[i])], 1u);
    __syncthreads();

    // ---- pass B: exclusive prefix sum over 1024 bins (4 bins/thread) ----
    unsigned h0 = hist[threadIdx.x * 4 + 0];
    unsigned h1 = hist[threadIdx.x * 4 + 1];
    unsigned h2 = hist[threadIdx.x * 4 + 2];
    unsigned h3 = hist[threadIdx.x * 4 + 3];
    unsigned local = h0 + h1 + h2 + h3;
    sscan[threadIdx.x] = local;
    __syncthreads();
    for (int st = 1; st < 256; st <<= 1) {
        unsigned v = (threadIdx.x >= (unsigned)st) ? sscan[threadIdx.x - st] : 0u;
        __syncthreads();
        sscan[threadIdx.x] += v;
        __syncthreads();
    }
    unsigned excl = sscan[threadIdx.x] - local;
    unsigned o0 = excl, o1 = o0 + h0, o2 = o1 + h1, o3 = o2 + h2;
    hist[threadIdx.x * 4 + 0] = o0;              // block-local cursors
    hist[threadIdx.x * 4 + 1] = o1;
    hist[threadIdx.x * 4 + 2] = o2;
    hist[threadIdx.x * 4 + 3] = o3;
    __syncthreads();

    unsigned* og = offs + (size_t)lb * ((size_t)nblk * NBKT + 1)
                        + (size_t)blk * NBKT;
    for (int i = threadIdx.x; i < NBKT; i += 256)      // coalesced
        og[i] = (unsigned)base + hist[i];
    if (blk == nblk - 1 && threadIdx.x == 0)
        offs[(size_t)lb * ((size_t)nblk * NBKT + 1) + (size_t)nblk * NBKT] =
            (unsigned)N;                         // sentinel
    __syncthreads();

    // ---- pass C: scatter into LDS (re-read input) ----
    for (int i = threadIdx.x; i < n4; i += 256) {
        float4 v  = ((const float4*)xb)[i];
        int4   cc = ((const int4*)tb)[i];
        unsigned k;
        k = canon_key(v.x); lout[atomicAdd(&hist[bucket_of(k, cc.x)], 1u)] = k;
        k = canon_key(v.y); lout[atomicAdd(&hist[bucket_of(k, cc.y)], 1u)] = k;
        k = canon_key(v.z); lout[atomicAdd(&hist[bucket_of(k, cc.z)], 1u)] = k;
        k = canon_key(v.w); lout[atomicAdd(&hist[bucket_of(k, cc.w)], 1u)] = k;
    }
    for (int i = (n4 << 2) + threadIdx.x; i < count; i += 256) {
        unsigned k = canon_key(xb[i]);
        lout[atomicAdd(&hist[bucket_of(k, tb[i])], 1u)] = k;
    }
    __syncthreads();

    // ---- pass D: coalesced write-back ----
    unsigned* kb = keysout + (size_t)lb * N + base;
    for (int i = threadIdx.x; i < n4; i += 256)
        ((uint4*)kb)[i] = ((const uint4*)lout)[i];
    for (int i = (n4 << 2) + threadIdx.x; i < count; i += 256)
        kb[i] = lout[i];
}

// Pass 2: one block per (batch,bucket). Gather the bucket's nblk contiguous
// segments from the dense array, build packed (count<<32 | key) LDS table,
// fold into best = max(count<<32 | (2^32-1 - ord(value))) -- max count,
// ties -> smallest value (reference tie-break). Also exact f64 sum + count.
__global__ void __launch_bounds__(256)
mode_kernel(const unsigned* __restrict__ keysout,
            const unsigned* __restrict__ offs, int nblk, long long N,
            int bbase,
            unsigned long long* __restrict__ best,   // [NUM_B*NUM_C], zeroed
            double* __restrict__ psum,               // [NUM_B*NBKT]
            unsigned* __restrict__ pcnt)             // [NUM_B*NBKT]
{
    __shared__ unsigned long long tab[TAB_SLOTS];    // 32 KiB
    __shared__ unsigned long long red[256];
    __shared__ double   dred[256];
    __shared__ unsigned cred[256];

    const unsigned lb  = blockIdx.x / NBKT;
    const unsigned bkt = blockIdx.x % NBKT;
    const unsigned c   = bkt >> 6;
    const unsigned b   = (unsigned)bbase + lb;

    for (int i = threadIdx.x; i < TAB_SLOTS; i += 256) tab[i] = 0ull;
    __syncthreads();

    const unsigned* ob = offs + (size_t)lb * ((size_t)nblk * NBKT + 1);
    const unsigned* kb = keysout + (size_t)lb * N;

    double ls = 0.0;
    unsigned lc = 0u;
    for (int seg = threadIdx.x; seg < nblk; seg += 256) {
        unsigned s = ob[(size_t)seg * NBKT + bkt];
        unsigned e = ob[(size_t)seg * NBKT + bkt + 1];  // bkt=1023 -> next row
        lc += e - s;
        for (unsigned i = s; i < e; ++i) {
            unsigned key = kb[i];
            ls += (double)__uint_as_float(key);
            unsigned h = hash_u32(key) & (TAB_SLOTS - 1);
            unsigned long long pk = (1ull << 32) | (unsigned long long)key;
            for (int p = 0; p < TAB_SLOTS; ++p) {       // bounded probe
                unsigned long long curv = tab[h];
                if (curv != 0ull && (unsigned)curv == key) {
                    atomicAdd(&tab[h], 1ull << 32); break;
                }
                if (curv == 0ull) {
                    unsigned long long old = atomicCAS(&tab[h], 0ull, pk);
                    if (old == 0ull) break;
                    if ((unsigned)old == key) {
                        atomicAdd(&tab[h], 1ull << 32); break;
                    }
                }
                h = (h + 1u) & (TAB_SLOTS - 1);
            }
        }
    }
    __syncthreads();

    unsigned long long lbst = 0ull;
    for (int s = threadIdx.x; s < TAB_SLOTS; s += 256) {
        unsigned long long curv = tab[s];
        if (curv) {
            unsigned k   = (unsigned)curv;
            unsigned ct  = (unsigned)(curv >> 32);
            unsigned ord = (k & 0x80000000u) ? ~k : (k | 0x80000000u);
            unsigned long long p = ((unsigned long long)ct << 32)
                                 | (unsigned long long)(0xFFFFFFFFu - ord);
            if (p > lbst) lbst = p;
        }
    }
    red[threadIdx.x]  = lbst;
    dred[threadIdx.x] = ls;
    cred[threadIdx.x] = lc;
    __syncthreads();
    for (int st = 128; st > 0; st >>= 1) {
        if (threadIdx.x < (unsigned)st) {
            if (red[threadIdx.x + st] > red[threadIdx.x])
                red[threadIdx.x] = red[threadIdx.x + st];
            dred[threadIdx.x] += dred[threadIdx.x + st];
            cred[threadIdx.x] += cred[threadIdx.x + st];
        }
        __syncthreads();
    }
    if (threadIdx.x == 0) {
        psum[b * NBKT + bkt] = dred[0];
        pcnt[b * NBKT + bkt] = cred[0];
        if (red[0]) atomicMax(&best[b * NUM_C + c], red[0]);
    }
}

// 128 threads, one per (b,c): fold 64 range-buckets, decode mode,
// out = sum_{b,c}(sum - cnt*mode) / (B*N).
__global__ void __launch_bounds__(128)
finalize_kernel(const double* __restrict__ psum,
                const unsigned* __restrict__ pcnt,
                const unsigned long long* __restrict__ best,
                float* __restrict__ out, double inv_total)
{
    __shared__ double acc[NUM_B * NUM_C];
    const int i = threadIdx.x;
    const int b = i >> 4, c = i & 15;

    double s = 0.0;
    unsigned long long cnt = 0ull;
    const double*   ps = psum + (size_t)b * NBKT + ((size_t)c << 6);
    const unsigned* pc = pcnt + (size_t)b * NBKT + ((size_t)c << 6);
    for (int r = 0; r < RANGES; ++r) { s += ps[r]; cnt += pc[r]; }

    double term = 0.0;
    if (cnt > 0ull) {
        unsigned long long p = best[i];
        unsigned ord = 0xFFFFFFFFu - (unsigned)(p & 0xFFFFFFFFull);
        unsigned ub  = (ord & 0x80000000u) ? (ord ^ 0x80000000u) : ~ord;
        float mode = __uint_as_float(ub);
        term = s - (double)cnt * (double)mode;
    }
    acc[i] = term;
    __syncthreads();
    for (int st = 64; st > 0; st >>= 1) {
        if (i < st) acc[i] += acc[i + st];
        __syncthreads();
    }
    if (i == 0) out[0] = (float)(acc[0] * inv_total);
}

extern "C" void kernel_launch(void* const* d_in, const int* in_sizes, int n_in,
                              void* d_out, int out_size, void* d_ws, size_t ws_size,
                              hipStream_t stream)
{
    const float* x = (const float*)d_in[0];
    const int*   t = (const int*)d_in[1];

    const long long total = in_sizes[0];
    const long long N = total / NUM_B;
    const int nblk = (int)((N + CHUNK - 1) / CHUNK);

    // Workspace: best 1K | psum 64K | pcnt 32K | keysout nb*N*4 | offs
    char* ws = (char*)d_ws;
    size_t off = 0;
    unsigned long long* best = (unsigned long long*)(ws + off);
    off += (size_t)NUM_B * NUM_C * 8;
    double* psum = (double*)(ws + off);
    off += (size_t)NUM_B * NBKT * 8;
    unsigned* pcnt = (unsigned*)(ws + off);
    off += (size_t)NUM_B * NBKT * 4;
    off = (off + 255) & ~(size_t)255;

    const size_t offs_per_b = (size_t)nblk * NBKT + 1;
    const size_t per_b = (size_t)N * 4 + offs_per_b * 4;
    size_t remaining = ws_size - off;
    int nb = (int)(remaining / per_b);
    if (nb < 1) nb = 1;                          // (ws known >= 76 MB; 1 fits)
    if (nb > NUM_B) nb = NUM_B;

    unsigned* keysout = (unsigned*)(ws + off);
    unsigned* offs    = (unsigned*)(ws + off + (size_t)nb * N * 4);

    hipMemsetAsync(best, 0, (size_t)NUM_B * NUM_C * 8, stream);
    for (int r = 0; r < NUM_B; r += nb) {
        int nbr = (NUM_B - r < nb) ? (NUM_B - r) : nb;
        scatter_kernel<<<nbr * nblk, 256, 0, stream>>>(
            x, t, N, r, nblk, keysout, offs);
        mode_kernel<<<nbr * NBKT, 256, 0, stream>>>(
            keysout, offs, nblk, N, r, best, psum, pcnt);
    }
    finalize_kernel<<<1, 128, 0, stream>>>(
        psum, pcnt, best, (float*)d_out,
        1.0 / ((double)NUM_B * (double)N));
}

// Round 5
// 367.653 us; speedup vs baseline: 5.6683x; 1.0504x over previous
//
#include <hip/hip_runtime.h>
#include <stdint.h>

#define NUM_C 16
#define NUM_B 8
#define RANGES 64                        // hash sub-ranges per class
#define NBKT (NUM_C * RANGES)            // 1024 buckets per batch
#define CHUNK 8192                       // items per scatter block
#define TAB_SLOTS 4096                   // LDS hash slots (load ~0.48)
#define MAX_SEGS 512                     // >= nblk (245 for N=2M)

__device__ __forceinline__ unsigned hash_u32(unsigned h) {
    h ^= h >> 16; h *= 0x85ebca6bu;
    h ^= h >> 13; h *= 0xc2b2ae35u;
    h ^= h >> 16;
    return h;
}

__device__ __forceinline__ unsigned canon_key(float v) {
    unsigned k = __float_as_uint(v);
    return (k == 0x80000000u) ? 0u : k;          // -0.0 == +0.0
}
__device__ __forceinline__ unsigned bucket_of(unsigned key, int c) {
    return ((unsigned)c << 6) | (hash_u32(key) >> 26);
}

// Pass 1: per-block counting sort (unchanged from R4, minus the sentinel).
// Dense output, exact counts, coalesced writes. offs[seg][bkt] = absolute
// start of (chunk seg, bucket bkt) run.
__global__ void __launch_bounds__(256)
scatter_kernel(const float* __restrict__ x, const int* __restrict__ t,
               long long N, int bbase, int nblk,
               unsigned* __restrict__ keysout,   // [nb][N] dense
               unsigned* __restrict__ offs)      // [nb][nblk][NBKT]
{
    __shared__ unsigned hist[NBKT];              // 4 KiB
    __shared__ unsigned lout[CHUNK];             // 32 KiB
    __shared__ unsigned sscan[256];              // 1 KiB

    const int lb   = blockIdx.x / nblk;
    const int blk  = blockIdx.x % nblk;
    const int b    = bbase + lb;
    const long long base = (long long)blk * CHUNK;
    const int count = (int)((N - base < CHUNK) ? (N - base) : CHUNK);

    const float* xb = x + (size_t)b * N + base;
    const int*   tb = t + (size_t)b * N + base;

    for (int i = threadIdx.x; i < NBKT; i += 256) hist[i] = 0u;
    __syncthreads();

    const bool vec_ok = ((N & 3) == 0);
    const int n4 = vec_ok ? (count >> 2) : 0;

    // ---- A: histogram ----
    for (int i = threadIdx.x; i < n4; i += 256) {
        float4 v  = ((const float4*)xb)[i];
        int4   cc = ((const int4*)tb)[i];
        atomicAdd(&hist[bucket_of(canon_key(v.x), cc.x)], 1u);
        atomicAdd(&hist[bucket_of(canon_key(v.y), cc.y)], 1u);
        atomicAdd(&hist[bucket_of(canon_key(v.z), cc.z)], 1u);
        atomicAdd(&hist[bucket_of(canon_key(v.w), cc.w)], 1u);
    }
    for (int i = (n4 << 2) + threadIdx.x; i < count; i += 256)
        atomicAdd(&hist[bucket_of(canon_key(xb[i]), tb[i])], 1u);
    __syncthreads();

    // ---- B: exclusive prefix sum (4 bins/thread) ----
    unsigned h0 = hist[threadIdx.x * 4 + 0];
    unsigned h1 = hist[threadIdx.x * 4 + 1];
    unsigned h2 = hist[threadIdx.x * 4 + 2];
    unsigned h3 = hist[threadIdx.x * 4 + 3];
    unsigned local = h0 + h1 + h2 + h3;
    sscan[threadIdx.x] = local;
    __syncthreads();
    for (int st = 1; st < 256; st <<= 1) {
        unsigned v = (threadIdx.x >= (unsigned)st) ? sscan[threadIdx.x - st] : 0u;
        __syncthreads();
        sscan[threadIdx.x] += v;
        __syncthreads();
    }
    unsigned excl = sscan[threadIdx.x] - local;
    unsigned o0 = excl, o1 = o0 + h0, o2 = o1 + h1, o3 = o2 + h2;
    hist[threadIdx.x * 4 + 0] = o0;
    hist[threadIdx.x * 4 + 1] = o1;
    hist[threadIdx.x * 4 + 2] = o2;
    hist[threadIdx.x * 4 + 3] = o3;
    __syncthreads();

    unsigned* og = offs + (size_t)lb * nblk * NBKT + (size_t)blk * NBKT;
    for (int i = threadIdx.x; i < NBKT; i += 256)      // coalesced
        og[i] = (unsigned)base + hist[i];
    __syncthreads();

    // ---- C: scatter into LDS (re-read input) ----
    for (int i = threadIdx.x; i < n4; i += 256) {
        float4 v  = ((const float4*)xb)[i];
        int4   cc = ((const int4*)tb)[i];
        unsigned k;
        k = canon_key(v.x); lout[atomicAdd(&hist[bucket_of(k, cc.x)], 1u)] = k;
        k = canon_key(v.y); lout[atomicAdd(&hist[bucket_of(k, cc.y)], 1u)] = k;
        k = canon_key(v.z); lout[atomicAdd(&hist[bucket_of(k, cc.z)], 1u)] = k;
        k = canon_key(v.w); lout[atomicAdd(&hist[bucket_of(k, cc.w)], 1u)] = k;
    }
    for (int i = (n4 << 2) + threadIdx.x; i < count; i += 256) {
        unsigned k = canon_key(xb[i]);
        lout[atomicAdd(&hist[bucket_of(k, tb[i])], 1u)] = k;
    }
    __syncthreads();

    // ---- D: coalesced write-back ----
    unsigned* kb = keysout + (size_t)lb * N + base;
    for (int i = threadIdx.x; i < n4; i += 256)
        ((uint4*)kb)[i] = ((const uint4*)lout)[i];
    for (int i = (n4 << 2) + threadIdx.x; i < count; i += 256)
        kb[i] = lout[i];
}

// Pass 1.5: transpose offs [seg][bkt] -> offsT [bkt][seg] so mode blocks
// read their segment-offset row coalesced (kills the 128 MB offs gather).
__global__ void __launch_bounds__(256)
transpose_kernel(const unsigned* __restrict__ offs,
                 unsigned* __restrict__ offsT, int nblk)
{
    __shared__ unsigned tile[32][33];
    const int lb   = blockIdx.z;
    const int seg0 = blockIdx.x * 32;
    const int bkt0 = blockIdx.y * 32;
    const unsigned* src = offs  + (size_t)lb * nblk * NBKT;
    unsigned*       dst = offsT + (size_t)lb * nblk * NBKT;
    const int tx = threadIdx.x & 31, ty = threadIdx.x >> 5;
    #pragma unroll
    for (int j = 0; j < 32; j += 8) {
        int seg = seg0 + ty + j;
        if (seg < nblk) tile[ty + j][tx] = src[(size_t)seg * NBKT + bkt0 + tx];
    }
    __syncthreads();
    #pragma unroll
    for (int j = 0; j < 32; j += 8) {
        int seg = seg0 + tx;
        if (seg < nblk)
            dst[(size_t)(bkt0 + ty + j) * nblk + seg] = tile[tx][ty + j];
    }
}

// Pass 2: one block per (batch,bucket). Segment offsets staged coalesced
// into LDS; 8 lanes cooperate per segment (flattened (seg,lane) slots) so
// gather reads coalesce within runs and LDS probe chains overlap across
// lanes. Packed (count<<32 | key) LDS table; fold into best =
// max(count<<32 | (2^32-1 - ord(value))): max count, ties -> min value.
__global__ void __launch_bounds__(256)
mode_kernel(const unsigned* __restrict__ keysout,
            const unsigned* __restrict__ offsT, int nblk, long long N,
            int bbase,
            unsigned long long* __restrict__ best,   // [NUM_B*NUM_C], zeroed
            double* __restrict__ psum,               // [NUM_B*NBKT]
            unsigned* __restrict__ pcnt)             // [NUM_B*NBKT]
{
    __shared__ unsigned long long tab[TAB_SLOTS];    // 32 KiB
    __shared__ unsigned sO[MAX_SEGS], sE[MAX_SEGS];  // 4 KiB
    __shared__ unsigned long long redb[4];
    __shared__ double reds[4];
    __shared__ unsigned redc[4];

    const unsigned lb  = blockIdx.x / NBKT;
    const unsigned bkt = blockIdx.x % NBKT;
    const unsigned c   = bkt >> 6;
    const unsigned b   = (unsigned)bbase + lb;

    for (int i = threadIdx.x; i < TAB_SLOTS; i += 256) tab[i] = 0ull;
    const unsigned* rowO = offsT + ((size_t)lb * NBKT + bkt) * nblk;
    for (int i = threadIdx.x; i < nblk; i += 256) {
        sO[i] = rowO[i];
        if (bkt < NBKT - 1) {
            sE[i] = rowO[nblk + i];                  // next bucket's row
        } else {
            long long e = (long long)(i + 1) * CHUNK;
            sE[i] = (unsigned)(e > N ? N : e);       // end of chunk
        }
    }
    __syncthreads();

    const unsigned* kb = keysout + (size_t)lb * N;
    double ls = 0.0;
    unsigned lc = 0u;

    const int nwork = nblk * 8;
    for (int w = threadIdx.x; w < nwork; w += 256) {
        const int seg  = w >> 3;
        const int lane = w & 7;
        const unsigned s = sO[seg], e = sE[seg];
        for (unsigned i = s + lane; i < e; i += 8) {
            unsigned key = kb[i];
            ls += (double)__uint_as_float(key);
            lc++;
            unsigned h = hash_u32(key) & (TAB_SLOTS - 1);
            unsigned long long pk = (1ull << 32) | (unsigned long long)key;
            for (;;) {
                unsigned long long curv = tab[h];
                if (curv != 0ull && (unsigned)curv == key) {
                    atomicAdd(&tab[h], 1ull << 32); break;
                }
                if (curv == 0ull) {
                    unsigned long long old = atomicCAS(&tab[h], 0ull, pk);
                    if (old == 0ull) break;
                    if ((unsigned)old == key) {
                        atomicAdd(&tab[h], 1ull << 32); break;
                    }
                }
                h = (h + 1u) & (TAB_SLOTS - 1);
            }
        }
    }
    __syncthreads();

    unsigned long long lbst = 0ull;
    for (int s2 = threadIdx.x; s2 < TAB_SLOTS; s2 += 256) {
        unsigned long long curv = tab[s2];
        if (curv) {
            unsigned k   = (unsigned)curv;
            unsigned ct  = (unsigned)(curv >> 32);
            unsigned ord = (k & 0x80000000u) ? ~k : (k | 0x80000000u);
            unsigned long long p = ((unsigned long long)ct << 32)
                                 | (unsigned long long)(0xFFFFFFFFu - ord);
            if (p > lbst) lbst = p;
        }
    }
    // wave-level reduction (width 64), then 4 wave results via LDS
    #pragma unroll
    for (int sh = 32; sh > 0; sh >>= 1) {
        unsigned long long ob = __shfl_down(lbst, sh);
        if (ob > lbst) lbst = ob;
        ls += __shfl_down(ls, sh);
        lc += __shfl_down(lc, sh);
    }
    const int wid = threadIdx.x >> 6;
    if ((threadIdx.x & 63) == 0) { redb[wid] = lbst; reds[wid] = ls; redc[wid] = lc; }
    __syncthreads();
    if (threadIdx.x == 0) {
        unsigned long long bb = 0ull; double ss = 0.0; unsigned cc = 0u;
        #pragma unroll
        for (int i = 0; i < 4; ++i) {
            if (redb[i] > bb) bb = redb[i];
            ss += reds[i]; cc += redc[i];
        }
        psum[b * NBKT + bkt] = ss;
        pcnt[b * NBKT + bkt] = cc;
        if (bb) atomicMax(&best[b * NUM_C + c], bb);
    }
}

// 128 threads, one per (b,c): fold 64 range-buckets, decode mode,
// out = sum_{b,c}(sum - cnt*mode) / (B*N).
__global__ void __launch_bounds__(128)
finalize_kernel(const double* __restrict__ psum,
                const unsigned* __restrict__ pcnt,
                const unsigned long long* __restrict__ best,
                float* __restrict__ out, double inv_total)
{
    __shared__ double acc[NUM_B * NUM_C];
    const int i = threadIdx.x;
    const int b = i >> 4, c = i & 15;

    double s = 0.0;
    unsigned long long cnt = 0ull;
    const double*   ps = psum + (size_t)b * NBKT + ((size_t)c << 6);
    const unsigned* pc = pcnt + (size_t)b * NBKT + ((size_t)c << 6);
    for (int r = 0; r < RANGES; ++r) { s += ps[r]; cnt += pc[r]; }

    double term = 0.0;
    if (cnt > 0ull) {
        unsigned long long p = best[i];
        unsigned ord = 0xFFFFFFFFu - (unsigned)(p & 0xFFFFFFFFull);
        unsigned ub  = (ord & 0x80000000u) ? (ord ^ 0x80000000u) : ~ord;
        float mode = __uint_as_float(ub);
        term = s - (double)cnt * (double)mode;
    }
    acc[i] = term;
    __syncthreads();
    for (int st = 64; st > 0; st >>= 1) {
        if (i < st) acc[i] += acc[i + st];
        __syncthreads();
    }
    if (i == 0) out[0] = (float)(acc[0] * inv_total);
}

extern "C" void kernel_launch(void* const* d_in, const int* in_sizes, int n_in,
                              void* d_out, int out_size, void* d_ws, size_t ws_size,
                              hipStream_t stream)
{
    const float* x = (const float*)d_in[0];
    const int*   t = (const int*)d_in[1];

    const long long total = in_sizes[0];
    const long long N = total / NUM_B;
    const int nblk = (int)((N + CHUNK - 1) / CHUNK);

    // Workspace: best 1K | psum 64K | pcnt 32K | keysout | offs | offsT
    char* ws = (char*)d_ws;
    size_t off = 0;
    unsigned long long* best = (unsigned long long*)(ws + off);
    off += (size_t)NUM_B * NUM_C * 8;
    double* psum = (double*)(ws + off);
    off += (size_t)NUM_B * NBKT * 8;
    unsigned* pcnt = (unsigned*)(ws + off);
    off += (size_t)NUM_B * NBKT * 4;
    off = (off + 255) & ~(size_t)255;

    const size_t offs_per_b = (size_t)nblk * NBKT;
    const size_t per_b = (size_t)N * 4 + offs_per_b * 8;   // keys + offs + offsT
    size_t remaining = ws_size - off;
    int nb = (int)(remaining / per_b);
    if (nb < 1) nb = 1;
    if (nb > NUM_B) nb = NUM_B;

    unsigned* keysout = (unsigned*)(ws + off);
    unsigned* offs    = (unsigned*)(ws + off + (size_t)nb * N * 4);
    unsigned* offsT   = offs + (size_t)nb * offs_per_b;

    hipMemsetAsync(best, 0, (size_t)NUM_B * NUM_C * 8, stream);
    for (int r = 0; r < NUM_B; r += nb) {
        int nbr = (NUM_B - r < nb) ? (NUM_B - r) : nb;
        scatter_kernel<<<nbr * nblk, 256, 0, stream>>>(
            x, t, N, r, nblk, keysout, offs);
        dim3 tg((nblk + 31) / 32, NBKT / 32, nbr);
        transpose_kernel<<<tg, 256, 0, stream>>>(offs, offsT, nblk);
        mode_kernel<<<nbr * NBKT, 256, 0, stream>>>(
            keysout, offsT, nblk, N, r, best, psum, pcnt);
    }
    finalize_kernel<<<1, 128, 0, stream>>>(
        psum, pcnt, best, (float*)d_out,
        1.0 / ((double)NUM_B * (double)N));
}